// Round 3
// baseline (2453.012 us; speedup 1.0000x reference)
//
#include <hip/hip_runtime.h>
#include <math.h>

typedef unsigned short u16;

constexpr int cB = 2;
constexpr int cS = 1024;
constexpr int cH = 1024;
constexpr int cNH = 16;
constexpr int cHD = 64;
constexpr int cW = 4;
constexpr int cL = (cW + 1) * cS; // 5120
constexpr float cEPS = 1e-5f;
constexpr float cNEG = -1e30f;

__device__ __forceinline__ float u2f(u16 u) {
  union { unsigned int i; float f; } x; x.i = ((unsigned int)u) << 16; return x.f;
}
__device__ __forceinline__ u16 f2u(float f) {
  union { float f; unsigned int i; } x; x.f = f;
  unsigned int i = x.i;
  i += 0x7fffu + ((i >> 16) & 1u); // RNE
  return (u16)(i >> 16);
}

// ---------------- LayerNorm (f32 -> f32): one block per row of 1024 ----------------
__global__ __launch_bounds__(256) void ln_kernel(
    const float* __restrict__ src, float* __restrict__ dst,
    const float* __restrict__ scale, const float* __restrict__ bias)
{
  int r = blockIdx.x;      // 0 .. cB*cS-1
  int t = threadIdx.x;
  const float* sp = src + (size_t)r * cH;
  float4 x = ((const float4*)sp)[t];
  float s1 = x.x + x.y + x.z + x.w;
  float s2 = x.x * x.x + x.y * x.y + x.z * x.z + x.w * x.w;
  #pragma unroll
  for (int off = 32; off > 0; off >>= 1) {
    s1 += __shfl_down(s1, off);
    s2 += __shfl_down(s2, off);
  }
  __shared__ float w1[4], w2[4];
  __shared__ float stat[2];
  int wid = t >> 6, lid = t & 63;
  if (lid == 0) { w1[wid] = s1; w2[wid] = s2; }
  __syncthreads();
  if (t == 0) {
    float a = w1[0] + w1[1] + w1[2] + w1[3];
    float b = w2[0] + w2[1] + w2[2] + w2[3];
    float mu = a * (1.f / cH);
    float var = b * (1.f / cH) - mu * mu;
    if (var < 0.f) var = 0.f;
    stat[0] = mu;
    stat[1] = rsqrtf(var + cEPS);
  }
  __syncthreads();
  float mu = stat[0], rs = stat[1];
  int h0 = t * 4;
  float4 sc = *(const float4*)(scale + h0);
  float4 bi = *(const float4*)(bias + h0);
  float4 o;
  o.x = (x.x - mu) * rs * sc.x + bi.x;
  o.y = (x.y - mu) * rs * sc.y + bi.y;
  o.z = (x.z - mu) * rs * sc.z + bi.z;
  o.w = (x.w - mu) * rs * sc.w + bi.w;
  *(float4*)(dst + (size_t)r * cH + h0) = o;
}

// ---------------- tiled GEMM: C[M,1024] = A(f32)[M,1024] @ W(f32)[1024,1024] ----------------
// kv=1: A rows gathered from cache (rows 0..4095 per batch) then normed (4096..5119).
// mode 0: f32 head-major out. mode 1: bf16 head-major out. mode 2: gated-residual epilogue (f32).
constexpr int BM = 64, BN = 64, BK = 32, LDT = 68;

__global__ __launch_bounds__(256) void gemm_kernel(
    const float* __restrict__ A, const float* __restrict__ Acache,
    const float* __restrict__ Wm,
    int rows_per_b, int kv, int mode,
    float* __restrict__ Cf, u16* __restrict__ Cb,
    const float* __restrict__ hidden, const float* __restrict__ cachefull,
    const float* __restrict__ gate, const float* __restrict__ lsc,
    float* __restrict__ outp)
{
  __shared__ __align__(16) float As[BK][LDT];
  __shared__ __align__(16) float Bs[BK][LDT];
  int t = threadIdx.x;
  int bx = blockIdx.x, by = blockIdx.y;
  int m0 = by * BM, n0 = bx * BN;

  int am = t >> 2, ak = (t & 3) * 8;
  int rga = m0 + am;
  int ab = rga / rows_per_b, al = rga - ab * rows_per_b;
  const float* arow;
  if (kv && al < cW * cS) {
    int w = al >> 10, s = al & (cS - 1);
    arow = Acache + ((size_t)((w * cB + ab) * cS + s)) * cH + ak;
  } else {
    int s = kv ? (al - cW * cS) : al;
    arow = A + ((size_t)(ab * cS + s)) * cH + ak;
  }
  int wk = t >> 3, wn = (t & 7) * 8;
  const float* wrow = Wm + (size_t)wk * cH + n0 + wn;

  int tx = t & 15, ty = t >> 4;
  float acc[4][4] = {};

  for (int k0 = 0; k0 < cH; k0 += BK) {
    float4 a0 = *(const float4*)(arow + k0);
    float4 a1 = *(const float4*)(arow + k0 + 4);
    float4 w0 = *(const float4*)(wrow + (size_t)k0 * cH);
    float4 w1 = *(const float4*)(wrow + (size_t)k0 * cH + 4);
    __syncthreads();  // previous iteration's LDS reads complete
    As[ak + 0][am] = a0.x; As[ak + 1][am] = a0.y;
    As[ak + 2][am] = a0.z; As[ak + 3][am] = a0.w;
    As[ak + 4][am] = a1.x; As[ak + 5][am] = a1.y;
    As[ak + 6][am] = a1.z; As[ak + 7][am] = a1.w;
    *(float4*)&Bs[wk][wn] = w0;
    *(float4*)&Bs[wk][wn + 4] = w1;
    __syncthreads();
    #pragma unroll
    for (int kk = 0; kk < BK; kk++) {
      float4 a4 = *(const float4*)&As[kk][ty * 4];
      float4 b4 = *(const float4*)&Bs[kk][tx * 4];
      float aa[4] = {a4.x, a4.y, a4.z, a4.w};
      float bb[4] = {b4.x, b4.y, b4.z, b4.w};
      #pragma unroll
      for (int i = 0; i < 4; i++)
        #pragma unroll
        for (int j = 0; j < 4; j++)
          acc[i][j] += aa[i] * bb[j];
    }
  }

  if (mode == 0) {
    // f32 head-major output: [b][h=bx][localrow][d]
    #pragma unroll
    for (int i = 0; i < 4; i++) {
      int rg = m0 + ty * 4 + i;
      int bo = rg / rows_per_b, lo = rg - bo * rows_per_b;
      float4 v = make_float4(acc[i][0], acc[i][1], acc[i][2], acc[i][3]);
      *(float4*)(Cf + (((size_t)(bo * cNH + bx) * rows_per_b + lo) * cHD) + tx * 4) = v;
    }
  } else if (mode == 1) {
    // bf16 head-major output
    #pragma unroll
    for (int i = 0; i < 4; i++) {
      int rg = m0 + ty * 4 + i;
      int bo = rg / rows_per_b, lo = rg - bo * rows_per_b;
      ushort4 o; u16* op = (u16*)&o;
      #pragma unroll
      for (int j = 0; j < 4; j++) op[j] = f2u(acc[i][j]);
      *(ushort4*)(Cb + (((size_t)(bo * cNH + bx) * rows_per_b + lo) * cHD) + tx * 4) = o;
    }
  } else {
    // fused gated residual epilogue, f32 out
    float gv[4], lv[4];
    #pragma unroll
    for (int j = 0; j < 4; j++) {
      int n = n0 + tx * 4 + j;
      gv[j] = 1.f / (1.f + __expf(-gate[n]));
      lv[j] = lsc[n];
    }
    #pragma unroll
    for (int i = 0; i < 4; i++) {
      int rg = m0 + ty * 4 + i;
      size_t base = (size_t)rg * cH + n0 + tx * 4;
      float4 hid = *(const float4*)(hidden + base);
      float4 cr  = *(const float4*)(cachefull + (size_t)3 * cB * cS * cH + base);
      float4 o;
      o.x = hid.x + lv[0] * (gv[0] * acc[i][0] + (1.f - gv[0]) * cr.x);
      o.y = hid.y + lv[1] * (gv[1] * acc[i][1] + (1.f - gv[1]) * cr.y);
      o.z = hid.z + lv[2] * (gv[2] * acc[i][2] + (1.f - gv[2]) * cr.z);
      o.w = hid.w + lv[3] * (gv[3] * acc[i][3] + (1.f - gv[3]) * cr.w);
      *(float4*)(outp + base) = o;
    }
  }
}

// ---------------- RoPE in-place, head-major [b*h][rows][64] ----------------
__global__ __launch_bounds__(256) void rope_f32(float* __restrict__ X, int rows) {
  size_t idx = (size_t)blockIdx.x * 256 + threadIdx.x;
  int d = (int)(idx & 31);
  size_t rest = idx >> 5;
  int row = (int)(rest % rows);
  size_t bh = rest / rows;
  float* xp = X + (bh * rows + row) * cHD;
  int pos = row & (cS - 1);
  float freq = exp2f(-(float)d * (13.287712379549449f / 32.f)); // 10000^(-d/32)
  float ang = (float)pos * freq;
  float sn, cs;
  sincosf(ang, &sn, &cs);
  float x1 = xp[d], x2 = xp[d + 32];
  xp[d] = x1 * cs - x2 * sn;
  xp[d + 32] = x1 * sn + x2 * cs;
}

__global__ __launch_bounds__(256) void rope_b16(u16* __restrict__ X, int rows) {
  size_t idx = (size_t)blockIdx.x * 256 + threadIdx.x;
  int d = (int)(idx & 31);
  size_t rest = idx >> 5;
  int row = (int)(rest % rows);
  size_t bh = rest / rows;
  u16* xp = X + (bh * rows + row) * cHD;
  int pos = row & (cS - 1);
  float freq = exp2f(-(float)d * (13.287712379549449f / 32.f));
  float ang = (float)pos * freq;
  float sn, cs;
  sincosf(ang, &sn, &cs);
  float x1 = u2f(xp[d]), x2 = u2f(xp[d + 32]);
  xp[d] = f2u(x1 * cs - x2 * sn);
  xp[d + 32] = f2u(x1 * sn + x2 * cs);
}

// ---------------- flash attention: TQ=32 q rows / block, chunks of CK=64 keys ----------------
constexpr int TQ = 32, CK = 64, PST = 36;

__global__ __launch_bounds__(256) void attn_kernel(
    const float* __restrict__ Q, const u16* __restrict__ K, const u16* __restrict__ V,
    float* __restrict__ ctx)
{
  __shared__ __align__(16) float ks[CK][cHD];
  __shared__ __align__(16) float vs[CK][cHD];
  __shared__ __align__(16) float ps[CK][PST];   // transposed scores/probs [c][r]
  __shared__ float mrow[TQ], lrow[TQ], arow[TQ];
  __shared__ float ssum[8][TQ];

  int t = threadIdx.x;
  int qt = blockIdx.x, h = blockIdx.y, b = blockIdx.z;
  const u16* kp = K + ((size_t)(b * cNH + h)) * cL * cHD;
  const u16* vp = V + ((size_t)(b * cNH + h)) * cL * cHD;

  int r = t & 31, cg = t >> 5;   // score mapping: thread = (row r, col-group cg)
  int d = t & 63, g = t >> 6;    // PV mapping: thread = (dim d, row-group g)

  const float* qp = Q + (((size_t)(b * cNH + h) * cS) + qt * TQ + r) * cHD;
  float4 qreg[16];               // q[r][0..63] in registers
  #pragma unroll
  for (int i = 0; i < 16; i++) qreg[i] = *(const float4*)(qp + i * 4);

  if (t < TQ) { mrow[t] = cNEG; lrow[t] = 0.f; }
  float oacc[8] = {};

  for (int kt = 0; kt < cL / CK; kt++) {
    __syncthreads();   // previous PV reads of vs/ps complete
    const u16* ksrc = kp + (size_t)kt * CK * cHD;
    const u16* vsrc = vp + (size_t)kt * CK * cHD;
    #pragma unroll
    for (int i = 0; i < 2; i++) {
      int e = (t + i * 256) * 8;
      int rr = e >> 6, cc = e & 63;
      uint4 kv4 = *(const uint4*)(ksrc + e);
      uint4 vv4 = *(const uint4*)(vsrc + e);
      u16* ku = (u16*)&kv4; u16* vu = (u16*)&vv4;
      *(float4*)&ks[rr][cc]     = make_float4(u2f(ku[0]), u2f(ku[1]), u2f(ku[2]), u2f(ku[3]));
      *(float4*)&ks[rr][cc + 4] = make_float4(u2f(ku[4]), u2f(ku[5]), u2f(ku[6]), u2f(ku[7]));
      *(float4*)&vs[rr][cc]     = make_float4(u2f(vu[0]), u2f(vu[1]), u2f(vu[2]), u2f(vu[3]));
      *(float4*)&vs[rr][cc + 4] = make_float4(u2f(vu[4]), u2f(vu[5]), u2f(vu[6]), u2f(vu[7]));
    }
    __syncthreads();
    // scores: thread computes 8 dots (row r x cols cg*8..cg*8+7)
    float sa[8] = {};
    #pragma unroll
    for (int d4 = 0; d4 < 16; d4++) {
      float4 qv = qreg[d4];
      #pragma unroll
      for (int j = 0; j < 8; j++) {
        float4 kv = *(const float4*)&ks[cg * 8 + j][d4 * 4];
        sa[j] += qv.x * kv.x + qv.y * kv.y + qv.z * kv.z + qv.w * kv.w;
      }
    }
    #pragma unroll
    for (int j = 0; j < 8; j++) ps[cg * 8 + j][r] = sa[j] * 0.125f;
    __syncthreads();
    // online-softmax row stats
    if (t < TQ) {
      float mold = mrow[t], mx = mold;
      #pragma unroll 8
      for (int c = 0; c < CK; c++) mx = fmaxf(mx, ps[c][t]);
      float al = __expf(mold - mx);   // first chunk: exp(-huge) == 0
      mrow[t] = mx; arow[t] = al; lrow[t] *= al;
    }
    __syncthreads();
    #pragma unroll
    for (int i = 0; i < 8; i++) oacc[i] *= arow[g * 8 + i];
    float mps = mrow[r];
    float psum = 0.f;
    #pragma unroll
    for (int j = 0; j < 8; j++) {
      float p = __expf(ps[cg * 8 + j][r] - mps);
      ps[cg * 8 + j][r] = p;
      psum += p;
    }
    ssum[cg][r] = psum;
    __syncthreads();
    if (t < TQ) {
      float s8 = 0.f;
      #pragma unroll
      for (int i = 0; i < 8; i++) s8 += ssum[i][t];
      lrow[t] += s8;
    }
    // PV: thread owns dim d for rows g*8..g*8+7
    #pragma unroll 8
    for (int c = 0; c < CK; c++) {
      float vv = vs[c][d];
      float4 p0 = *(const float4*)&ps[c][g * 8];
      float4 p1 = *(const float4*)&ps[c][g * 8 + 4];
      oacc[0] += p0.x * vv; oacc[1] += p0.y * vv; oacc[2] += p0.z * vv; oacc[3] += p0.w * vv;
      oacc[4] += p1.x * vv; oacc[5] += p1.y * vv; oacc[6] += p1.z * vv; oacc[7] += p1.w * vv;
    }
  }
  __syncthreads();
  #pragma unroll
  for (int i = 0; i < 8; i++) {
    int rr = g * 8 + i;
    float val = oacc[i] / lrow[rr];
    ctx[(((size_t)b * cS + qt * TQ + rr) * cH) + h * cHD + d] = val;
  }
}

extern "C" void kernel_launch(void* const* d_in, const int* in_sizes, int n_in,
                              void* d_out, int out_size, void* d_ws, size_t ws_size,
                              hipStream_t stream)
{
  const float* hidden = (const float*)d_in[0];
  const float* cache  = (const float*)d_in[1];
  const float* ln_s   = (const float*)d_in[2];
  const float* ln_b   = (const float*)d_in[3];
  const float* Wq     = (const float*)d_in[4];
  const float* Wk     = (const float*)d_in[5];
  const float* Wv     = (const float*)d_in[6];
  const float* Wo     = (const float*)d_in[7];
  const float* gate   = (const float*)d_in[8];
  const float* lsc    = (const float*)d_in[9];
  float* outp = (float*)d_out;

  char* wsb = (char*)d_ws;
  size_t off = 0;
  auto alloc = [&](size_t bytes) -> void* {
    void* p = wsb + off;
    off += (bytes + 255) & ~(size_t)255;
    return p;
  };
  float* normed = (float*)alloc((size_t)cB * cS * cH * 4);          // 8 MB
  float* qb     = (float*)alloc((size_t)cB * cNH * cS * cHD * 4);   // 8 MB
  u16*   kb     = (u16*)  alloc((size_t)cB * cNH * cL * cHD * 2);   // 20 MB
  u16*   vb     = (u16*)  alloc((size_t)cB * cNH * cL * cHD * 2);   // 20 MB
  float* ctx    = (float*)alloc((size_t)cB * cS * cH * 4);          // 8 MB
  // total ~64 MB

  // 1) pre-norm -> normed [B,S,H]
  ln_kernel<<<cB * cS, 256, 0, stream>>>(hidden, normed, ln_s, ln_b);
  // 2) new_cache[0:3] = cache[1:4] (contiguous flat copy)
  hipMemcpyAsync(outp + (size_t)cB * cS * cH, cache + (size_t)cB * cS * cH,
                 (size_t)(cW - 1) * cB * cS * cH * sizeof(float),
                 hipMemcpyDeviceToDevice, stream);

  // 3) Q/K/V projections (head-major outputs; Q f32, K/V bf16)
  gemm_kernel<<<dim3(16, (cB * cS) / BM), 256, 0, stream>>>(
      normed, nullptr, Wq, cS, 0, 0, qb, nullptr,
      nullptr, nullptr, nullptr, nullptr, nullptr);
  gemm_kernel<<<dim3(16, (cB * cL) / BM), 256, 0, stream>>>(
      normed, cache, Wk, cL, 1, 1, nullptr, kb,
      nullptr, nullptr, nullptr, nullptr, nullptr);
  gemm_kernel<<<dim3(16, (cB * cL) / BM), 256, 0, stream>>>(
      normed, cache, Wv, cL, 1, 1, nullptr, vb,
      nullptr, nullptr, nullptr, nullptr, nullptr);

  // 4) RoPE (in-place)
  rope_f32<<<(cB * cNH * cS * 32) / 256, 256, 0, stream>>>(qb, cS);
  rope_b16<<<(cB * cNH * cL * 32) / 256, 256, 0, stream>>>(kb, cL);

  // 5) attention -> ctx (f32, token-major)
  attn_kernel<<<dim3(cS / TQ, cNH, cB), 256, 0, stream>>>(qb, kb, vb, ctx);

  // 6) ctx @ Wo with fused gated residual -> output f32
  gemm_kernel<<<dim3(16, (cB * cS) / BM), 256, 0, stream>>>(
      ctx, nullptr, Wo, cS, 0, 2, nullptr, nullptr,
      hidden, cache, gate, lsc, outp);

  // 7) final layernorm -> new_cache slot 3
  ln_kernel<<<cB * cS, 256, 0, stream>>>(outp, outp + (size_t)cW * cB * cS * cH, ln_s, ln_b);
}

// Round 4
// 1147.671 us; speedup vs baseline: 2.1374x; 2.1374x over previous
//
#include <hip/hip_runtime.h>
#include <math.h>

typedef unsigned short u16;

constexpr int cB = 2;
constexpr int cS = 1024;
constexpr int cH = 1024;
constexpr int cNH = 16;
constexpr int cHD = 64;
constexpr int cW = 4;
constexpr int cL = (cW + 1) * cS; // 5120
constexpr float cEPS = 1e-5f;

typedef short s16x8 __attribute__((ext_vector_type(8)));   // 8 bf16 (4 VGPRs)
typedef float f32x4 __attribute__((ext_vector_type(4)));   // MFMA C/D

__device__ __forceinline__ float u2f(u16 u) {
  union { unsigned int i; float f; } x; x.i = ((unsigned int)u) << 16; return x.f;
}
__device__ __forceinline__ u16 f2u(float f) {
  union { float f; unsigned int i; } x; x.f = f;
  unsigned int i = x.i;
  i += 0x7fffu + ((i >> 16) & 1u); // RNE
  return (u16)(i >> 16);
}
__device__ __forceinline__ s16x8 ld_frag(const u16* p) {
  uint4 v = *(const uint4*)p;
  union { uint4 u; s16x8 s; } c; c.u = v; return c.s;
}

// ---------------- LayerNorm (f32 -> f32): one block per row of 1024 ----------------
__global__ __launch_bounds__(256) void ln_kernel(
    const float* __restrict__ src, float* __restrict__ dst,
    const float* __restrict__ scale, const float* __restrict__ bias)
{
  int r = blockIdx.x;      // 0 .. cB*cS-1
  int t = threadIdx.x;
  const float* sp = src + (size_t)r * cH;
  float4 x = ((const float4*)sp)[t];
  float s1 = x.x + x.y + x.z + x.w;
  float s2 = x.x * x.x + x.y * x.y + x.z * x.z + x.w * x.w;
  #pragma unroll
  for (int off = 32; off > 0; off >>= 1) {
    s1 += __shfl_down(s1, off);
    s2 += __shfl_down(s2, off);
  }
  __shared__ float w1[4], w2[4];
  __shared__ float stat[2];
  int wid = t >> 6, lid = t & 63;
  if (lid == 0) { w1[wid] = s1; w2[wid] = s2; }
  __syncthreads();
  if (t == 0) {
    float a = w1[0] + w1[1] + w1[2] + w1[3];
    float b = w2[0] + w2[1] + w2[2] + w2[3];
    float mu = a * (1.f / cH);
    float var = b * (1.f / cH) - mu * mu;
    if (var < 0.f) var = 0.f;
    stat[0] = mu;
    stat[1] = rsqrtf(var + cEPS);
  }
  __syncthreads();
  float mu = stat[0], rs = stat[1];
  int h0 = t * 4;
  float4 sc = *(const float4*)(scale + h0);
  float4 bi = *(const float4*)(bias + h0);
  float4 o;
  o.x = (x.x - mu) * rs * sc.x + bi.x;
  o.y = (x.y - mu) * rs * sc.y + bi.y;
  o.z = (x.z - mu) * rs * sc.z + bi.z;
  o.w = (x.w - mu) * rs * sc.w + bi.w;
  *(float4*)(dst + (size_t)r * cH + h0) = o;
}

// ---------------- tiled GEMM: C[M,1024] = A(f32)[M,1024] @ W(f32)[1024,1024] ----------------
// kv=1: A rows gathered from cache (rows 0..4095 per batch) then normed (4096..5119).
// mode 1: bf16 head-major out [b][h=bx][localrow][d].
// mode 2: gated-residual epilogue (f32 -> outp).
// mode 3: bf16 TRANSPOSED head-major out [b][h=bx][d][localrow]  (for V^T).
constexpr int BM = 64, BN = 64, BK = 32, LDT = 68;

__global__ __launch_bounds__(256) void gemm_kernel(
    const float* __restrict__ A, const float* __restrict__ Acache,
    const float* __restrict__ Wm,
    int rows_per_b, int kv, int mode,
    u16* __restrict__ Cb,
    const float* __restrict__ hidden, const float* __restrict__ cachefull,
    const float* __restrict__ gate, const float* __restrict__ lsc,
    float* __restrict__ outp)
{
  __shared__ __align__(16) float As[BK][LDT];
  __shared__ __align__(16) float Bs[BK][LDT];
  int t = threadIdx.x;
  int bx = blockIdx.x, by = blockIdx.y;
  int m0 = by * BM, n0 = bx * BN;

  int am = t >> 2, ak = (t & 3) * 8;
  int rga = m0 + am;
  int ab = rga / rows_per_b, al = rga - ab * rows_per_b;
  const float* arow;
  if (kv && al < cW * cS) {
    int w = al >> 10, s = al & (cS - 1);
    arow = Acache + ((size_t)((w * cB + ab) * cS + s)) * cH + ak;
  } else {
    int s = kv ? (al - cW * cS) : al;
    arow = A + ((size_t)(ab * cS + s)) * cH + ak;
  }
  int wk = t >> 3, wn = (t & 7) * 8;
  const float* wrow = Wm + (size_t)wk * cH + n0 + wn;

  int tx = t & 15, ty = t >> 4;
  float acc[4][4] = {};

  for (int k0 = 0; k0 < cH; k0 += BK) {
    float4 a0 = *(const float4*)(arow + k0);
    float4 a1 = *(const float4*)(arow + k0 + 4);
    float4 w0 = *(const float4*)(wrow + (size_t)k0 * cH);
    float4 w1 = *(const float4*)(wrow + (size_t)k0 * cH + 4);
    __syncthreads();  // previous iteration's LDS reads complete
    As[ak + 0][am] = a0.x; As[ak + 1][am] = a0.y;
    As[ak + 2][am] = a0.z; As[ak + 3][am] = a0.w;
    As[ak + 4][am] = a1.x; As[ak + 5][am] = a1.y;
    As[ak + 6][am] = a1.z; As[ak + 7][am] = a1.w;
    *(float4*)&Bs[wk][wn] = w0;
    *(float4*)&Bs[wk][wn + 4] = w1;
    __syncthreads();
    #pragma unroll
    for (int kk = 0; kk < BK; kk++) {
      float4 a4 = *(const float4*)&As[kk][ty * 4];
      float4 b4 = *(const float4*)&Bs[kk][tx * 4];
      float aa[4] = {a4.x, a4.y, a4.z, a4.w};
      float bb[4] = {b4.x, b4.y, b4.z, b4.w};
      #pragma unroll
      for (int i = 0; i < 4; i++)
        #pragma unroll
        for (int j = 0; j < 4; j++)
          acc[i][j] += aa[i] * bb[j];
    }
  }

  if (mode == 1) {
    // bf16 head-major output
    #pragma unroll
    for (int i = 0; i < 4; i++) {
      int rg = m0 + ty * 4 + i;
      int bo = rg / rows_per_b, lo = rg - bo * rows_per_b;
      ushort4 o; u16* op = (u16*)&o;
      #pragma unroll
      for (int j = 0; j < 4; j++) op[j] = f2u(acc[i][j]);
      *(ushort4*)(Cb + (((size_t)(bo * cNH + bx) * rows_per_b + lo) * cHD) + tx * 4) = o;
    }
  } else if (mode == 3) {
    // bf16 transposed head-major (V^T): [b][h=bx][d=tx*4+j][l=lo..lo+3]
    int rg0 = m0 + ty * 4;
    int bo = rg0 / rows_per_b, lo = rg0 - bo * rows_per_b;
    #pragma unroll
    for (int j = 0; j < 4; j++) {
      ushort4 o; u16* op = (u16*)&o;
      #pragma unroll
      for (int i = 0; i < 4; i++) op[i] = f2u(acc[i][j]);
      *(ushort4*)(Cb + ((size_t)(bo * cNH + bx) * cHD + tx * 4 + j) * rows_per_b + lo) = o;
    }
  } else {
    // fused gated residual epilogue, f32 out
    float gv[4], lv[4];
    #pragma unroll
    for (int j = 0; j < 4; j++) {
      int n = n0 + tx * 4 + j;
      gv[j] = 1.f / (1.f + __expf(-gate[n]));
      lv[j] = lsc[n];
    }
    #pragma unroll
    for (int i = 0; i < 4; i++) {
      int rg = m0 + ty * 4 + i;
      size_t base = (size_t)rg * cH + n0 + tx * 4;
      float4 hid = *(const float4*)(hidden + base);
      float4 cr  = *(const float4*)(cachefull + (size_t)3 * cB * cS * cH + base);
      float4 o;
      o.x = hid.x + lv[0] * (gv[0] * acc[i][0] + (1.f - gv[0]) * cr.x);
      o.y = hid.y + lv[1] * (gv[1] * acc[i][1] + (1.f - gv[1]) * cr.y);
      o.z = hid.z + lv[2] * (gv[2] * acc[i][2] + (1.f - gv[2]) * cr.z);
      o.w = hid.w + lv[3] * (gv[3] * acc[i][3] + (1.f - gv[3]) * cr.w);
      *(float4*)(outp + base) = o;
    }
  }
}

// ---------------- RoPE in-place on head-major bf16 [b*h][rows][64] ----------------
__global__ __launch_bounds__(256) void rope_b16(u16* __restrict__ X, int rows) {
  size_t idx = (size_t)blockIdx.x * 256 + threadIdx.x;
  int d = (int)(idx & 31);
  size_t rest = idx >> 5;
  int row = (int)(rest % rows);
  size_t bh = rest / rows;
  u16* xp = X + (bh * rows + row) * cHD;
  int pos = row & (cS - 1);
  float freq = exp2f(-(float)d * (13.287712379549449f / 32.f)); // 10000^(-d/32)
  float ang = (float)pos * freq;
  float sn, cs;
  sincosf(ang, &sn, &cs);
  float x1 = u2f(xp[d]), x2 = u2f(xp[d + 32]);
  xp[d] = f2u(x1 * cs - x2 * sn);
  xp[d + 32] = f2u(x1 * sn + x2 * cs);
}

// ---------------- MFMA flash attention ----------------
// Block = 4 waves, 64 q rows (16/wave).  Chunks of CK=64 keys.
// Q,K bf16 head-major [b][h][row][64]; V bf16 TRANSPOSED [b][h][d][cL]; ctx f32 token-major.
constexpr int ACK = 64;
constexpr int PLD = 72;   // P-tile row stride (u16): 144 B, 16B-aligned reads

__global__ __launch_bounds__(256) void attn_mfma(
    const u16* __restrict__ Q, const u16* __restrict__ K, const u16* __restrict__ Vt,
    float* __restrict__ ctx)
{
  __shared__ u16 pbuf[4][16 * PLD];

  int t = threadIdx.x;
  int wave = t >> 6, lane = t & 63;
  int l15 = lane & 15, quad = lane >> 4;
  int qt = blockIdx.x, h = blockIdx.y, b = blockIdx.z;
  int q0 = qt * 64 + wave * 16;

  const u16* qp = Q + ((size_t)(b * cNH + h) * cS + q0) * cHD;
  const u16* kp = K + (size_t)(b * cNH + h) * cL * cHD;
  const u16* vp = Vt + (size_t)(b * cNH + h) * cHD * cL;
  u16* pw = pbuf[wave];

  // A-frags: Q[q=l15][d=quad*8+j], two K=32 steps over d
  s16x8 qf0 = ld_frag(qp + (size_t)l15 * cHD + quad * 8);
  s16x8 qf1 = ld_frag(qp + (size_t)l15 * cHD + 32 + quad * 8);

  f32x4 oacc[4] = {};                       // [dtile]: rows quad*4+i, col d=dtile*16+l15
  float mrow[4], lrow[4];
  #pragma unroll
  for (int i = 0; i < 4; i++) { mrow[i] = -1e30f; lrow[i] = 0.f; }

  constexpr float SCL = 0.125f * 1.4426950408889634f;  // (1/sqrt(64)) * log2(e)

  for (int kt = 0; kt < cL / ACK; kt++) {
    const u16* kc = kp + (size_t)kt * ACK * cHD;
    // ---- scores: 4 n-tiles of 16 keys, K-dim = 64 d (2 MFMA each) ----
    f32x4 sc[4];
    #pragma unroll
    for (int nt = 0; nt < 4; nt++) {
      s16x8 kf0 = ld_frag(kc + (size_t)(nt * 16 + l15) * cHD + quad * 8);
      s16x8 kf1 = ld_frag(kc + (size_t)(nt * 16 + l15) * cHD + 32 + quad * 8);
      f32x4 a = {};
      a = __builtin_amdgcn_mfma_f32_16x16x32_bf16(qf0, kf0, a, 0, 0, 0);
      a = __builtin_amdgcn_mfma_f32_16x16x32_bf16(qf1, kf1, a, 0, 0, 0);
      sc[nt] = a * SCL;     // base-2 softmax scaling
    }
    // ---- row max (in-lane over n-tiles, then across the 16-lane col group) ----
    float mx[4];
    #pragma unroll
    for (int i = 0; i < 4; i++)
      mx[i] = fmaxf(fmaxf(sc[0][i], sc[1][i]), fmaxf(sc[2][i], sc[3][i]));
    #pragma unroll
    for (int off = 1; off < 16; off <<= 1)
      #pragma unroll
      for (int i = 0; i < 4; i++) mx[i] = fmaxf(mx[i], __shfl_xor(mx[i], off));
    float alpha[4];
    #pragma unroll
    for (int i = 0; i < 4; i++) {
      float mn = fmaxf(mrow[i], mx[i]);
      alpha[i] = exp2f(mrow[i] - mn);
      mrow[i] = mn;
    }
    // ---- exp + row sum; write P (bf16) into per-wave LDS tile ----
    float ps[4] = {};
    #pragma unroll
    for (int nt = 0; nt < 4; nt++)
      #pragma unroll
      for (int i = 0; i < 4; i++) {
        float p = exp2f(sc[nt][i] - mrow[i]);
        ps[i] += p;
        pw[(quad * 4 + i) * PLD + nt * 16 + l15] = f2u(p);
      }
    #pragma unroll
    for (int off = 1; off < 16; off <<= 1)
      #pragma unroll
      for (int i = 0; i < 4; i++) ps[i] += __shfl_xor(ps[i], off);
    #pragma unroll
    for (int i = 0; i < 4; i++) lrow[i] = lrow[i] * alpha[i] + ps[i];
    // ---- rescale O ----
    #pragma unroll
    for (int dt = 0; dt < 4; dt++)
      #pragma unroll
      for (int i = 0; i < 4; i++) oacc[dt][i] *= alpha[i];
    // ---- PV: A = P (from LDS, A-layout), B = Vt rows (contiguous keys) ----
    s16x8 pf0 = *(const s16x8*)&pw[l15 * PLD + quad * 8];        // keys 0..31
    s16x8 pf1 = *(const s16x8*)&pw[l15 * PLD + 32 + quad * 8];   // keys 32..63
    #pragma unroll
    for (int dt = 0; dt < 4; dt++) {
      const u16* vr = vp + (size_t)(dt * 16 + l15) * cL + kt * ACK;
      s16x8 vf0 = ld_frag(vr + quad * 8);
      s16x8 vf1 = ld_frag(vr + 32 + quad * 8);
      oacc[dt] = __builtin_amdgcn_mfma_f32_16x16x32_bf16(pf0, vf0, oacc[dt], 0, 0, 0);
      oacc[dt] = __builtin_amdgcn_mfma_f32_16x16x32_bf16(pf1, vf1, oacc[dt], 0, 0, 0);
    }
  }
  // ---- epilogue: ctx[b][q][h*64+d] = O / l ----
  #pragma unroll
  for (int i = 0; i < 4; i++) {
    float inv = 1.f / lrow[i];
    int q = q0 + quad * 4 + i;
    float* crow = ctx + ((size_t)b * cS + q) * cH + h * cHD;
    #pragma unroll
    for (int dt = 0; dt < 4; dt++)
      crow[dt * 16 + l15] = oacc[dt][i] * inv;
  }
}

extern "C" void kernel_launch(void* const* d_in, const int* in_sizes, int n_in,
                              void* d_out, int out_size, void* d_ws, size_t ws_size,
                              hipStream_t stream)
{
  const float* hidden = (const float*)d_in[0];
  const float* cache  = (const float*)d_in[1];
  const float* ln_s   = (const float*)d_in[2];
  const float* ln_b   = (const float*)d_in[3];
  const float* Wq     = (const float*)d_in[4];
  const float* Wk     = (const float*)d_in[5];
  const float* Wv     = (const float*)d_in[6];
  const float* Wo     = (const float*)d_in[7];
  const float* gate   = (const float*)d_in[8];
  const float* lsc    = (const float*)d_in[9];
  float* outp = (float*)d_out;

  char* wsb = (char*)d_ws;
  size_t off = 0;
  auto alloc = [&](size_t bytes) -> void* {
    void* p = wsb + off;
    off += (bytes + 255) & ~(size_t)255;
    return p;
  };
  float* normed = (float*)alloc((size_t)cB * cS * cH * 4);          // 8 MB
  u16*   qb     = (u16*)  alloc((size_t)cB * cNH * cS * cHD * 2);   // 4 MB
  u16*   kb     = (u16*)  alloc((size_t)cB * cNH * cL * cHD * 2);   // 20 MB
  u16*   vt     = (u16*)  alloc((size_t)cB * cNH * cL * cHD * 2);   // 20 MB (transposed)
  float* ctx    = (float*)alloc((size_t)cB * cS * cH * 4);          // 8 MB

  // 1) pre-norm -> normed [B,S,H]
  ln_kernel<<<cB * cS, 256, 0, stream>>>(hidden, normed, ln_s, ln_b);
  // 2) new_cache[0:3] = cache[1:4] (contiguous flat copy)
  hipMemcpyAsync(outp + (size_t)cB * cS * cH, cache + (size_t)cB * cS * cH,
                 (size_t)(cW - 1) * cB * cS * cH * sizeof(float),
                 hipMemcpyDeviceToDevice, stream);

  // 3) Q/K/V projections: Q,K bf16 head-major; V bf16 transposed head-major
  gemm_kernel<<<dim3(16, (cB * cS) / BM), 256, 0, stream>>>(
      normed, nullptr, Wq, cS, 0, 1, qb, nullptr, nullptr, nullptr, nullptr, nullptr);
  gemm_kernel<<<dim3(16, (cB * cL) / BM), 256, 0, stream>>>(
      normed, cache, Wk, cL, 1, 1, kb, nullptr, nullptr, nullptr, nullptr, nullptr);
  gemm_kernel<<<dim3(16, (cB * cL) / BM), 256, 0, stream>>>(
      normed, cache, Wv, cL, 1, 3, vt, nullptr, nullptr, nullptr, nullptr, nullptr);

  // 4) RoPE on Q and K (V not roped)
  rope_b16<<<(cB * cNH * cS * 32) / 256, 256, 0, stream>>>(qb, cS);
  rope_b16<<<(cB * cNH * cL * 32) / 256, 256, 0, stream>>>(kb, cL);

  // 5) MFMA flash attention -> ctx (f32, token-major)
  attn_mfma<<<dim3(cS / 64, cNH, cB), 256, 0, stream>>>(qb, kb, vt, ctx);

  // 6) ctx @ Wo with fused gated residual -> output f32
  gemm_kernel<<<dim3(16, (cB * cS) / BM), 256, 0, stream>>>(
      ctx, nullptr, Wo, cS, 0, 2, nullptr, hidden, cache, gate, lsc, outp);

  // 7) final layernorm -> new_cache slot 3
  ln_kernel<<<cB * cS, 256, 0, stream>>>(outp, outp + (size_t)cW * cB * cS * cH, ln_s, ln_b);
}

// Round 5
// 625.186 us; speedup vs baseline: 3.9236x; 1.8357x over previous
//
#include <hip/hip_runtime.h>
#include <math.h>

typedef unsigned short u16;

constexpr int cB = 2;
constexpr int cS = 1024;
constexpr int cH = 1024;
constexpr int cNH = 16;
constexpr int cHD = 64;
constexpr int cW = 4;
constexpr int cL = (cW + 1) * cS; // 5120
constexpr float cEPS = 1e-5f;

typedef short s16x8 __attribute__((ext_vector_type(8)));   // 8 bf16 (4 VGPRs)
typedef float f32x4 __attribute__((ext_vector_type(4)));   // MFMA C/D

__device__ __forceinline__ float u2f(u16 u) {
  union { unsigned int i; float f; } x; x.i = ((unsigned int)u) << 16; return x.f;
}
__device__ __forceinline__ u16 f2u(float f) {
  union { float f; unsigned int i; } x; x.f = f;
  unsigned int i = x.i;
  i += 0x7fffu + ((i >> 16) & 1u); // RNE
  return (u16)(i >> 16);
}
__device__ __forceinline__ s16x8 ld_frag(const u16* p) {
  uint4 v = *(const uint4*)p;
  union { uint4 u; s16x8 s; } c; c.u = v; return c.s;
}

// ---------------- LayerNorm f32 -> f32 (final LN) ----------------
__global__ __launch_bounds__(256) void ln_f32(
    const float* __restrict__ src, float* __restrict__ dst,
    const float* __restrict__ scale, const float* __restrict__ bias)
{
  int r = blockIdx.x;
  int t = threadIdx.x;
  const float* sp = src + (size_t)r * cH;
  float4 x = ((const float4*)sp)[t];
  float s1 = x.x + x.y + x.z + x.w;
  float s2 = x.x * x.x + x.y * x.y + x.z * x.z + x.w * x.w;
  #pragma unroll
  for (int off = 32; off > 0; off >>= 1) {
    s1 += __shfl_down(s1, off);
    s2 += __shfl_down(s2, off);
  }
  __shared__ float w1[4], w2[4];
  __shared__ float stat[2];
  int wid = t >> 6, lid = t & 63;
  if (lid == 0) { w1[wid] = s1; w2[wid] = s2; }
  __syncthreads();
  if (t == 0) {
    float a = w1[0] + w1[1] + w1[2] + w1[3];
    float b = w2[0] + w2[1] + w2[2] + w2[3];
    float mu = a * (1.f / cH);
    float var = b * (1.f / cH) - mu * mu;
    if (var < 0.f) var = 0.f;
    stat[0] = mu; stat[1] = rsqrtf(var + cEPS);
  }
  __syncthreads();
  float mu = stat[0], rs = stat[1];
  int h0 = t * 4;
  float4 sc = *(const float4*)(scale + h0);
  float4 bi = *(const float4*)(bias + h0);
  float4 o;
  o.x = (x.x - mu) * rs * sc.x + bi.x;
  o.y = (x.y - mu) * rs * sc.y + bi.y;
  o.z = (x.z - mu) * rs * sc.z + bi.z;
  o.w = (x.w - mu) * rs * sc.w + bi.w;
  *(float4*)(dst + (size_t)r * cH + h0) = o;
}

// ---------------- LayerNorm f32 -> bf16 into kvin tail ----------------
__global__ __launch_bounds__(256) void ln_bf16(
    const float* __restrict__ src, u16* __restrict__ kvin,
    const float* __restrict__ scale, const float* __restrict__ bias)
{
  int r = blockIdx.x;            // 0..cB*cS-1
  int t = threadIdx.x;
  const float* sp = src + (size_t)r * cH;
  float4 x = ((const float4*)sp)[t];
  float s1 = x.x + x.y + x.z + x.w;
  float s2 = x.x * x.x + x.y * x.y + x.z * x.z + x.w * x.w;
  #pragma unroll
  for (int off = 32; off > 0; off >>= 1) {
    s1 += __shfl_down(s1, off);
    s2 += __shfl_down(s2, off);
  }
  __shared__ float w1[4], w2[4];
  __shared__ float stat[2];
  int wid = t >> 6, lid = t & 63;
  if (lid == 0) { w1[wid] = s1; w2[wid] = s2; }
  __syncthreads();
  if (t == 0) {
    float a = w1[0] + w1[1] + w1[2] + w1[3];
    float b = w2[0] + w2[1] + w2[2] + w2[3];
    float mu = a * (1.f / cH);
    float var = b * (1.f / cH) - mu * mu;
    if (var < 0.f) var = 0.f;
    stat[0] = mu; stat[1] = rsqrtf(var + cEPS);
  }
  __syncthreads();
  float mu = stat[0], rs = stat[1];
  int h0 = t * 4;
  float4 sc = *(const float4*)(scale + h0);
  float4 bi = *(const float4*)(bias + h0);
  int b = r >> 10, s = r & (cS - 1);
  u16* dp = kvin + ((size_t)(b * cL + cW * cS + s)) * cH + h0;
  ushort4 o; u16* op = (u16*)&o;
  op[0] = f2u((x.x - mu) * rs * sc.x + bi.x);
  op[1] = f2u((x.y - mu) * rs * sc.y + bi.y);
  op[2] = f2u((x.z - mu) * rs * sc.z + bi.z);
  op[3] = f2u((x.w - mu) * rs * sc.w + bi.w);
  *(ushort4*)dp = o;
}

// -------- cache f32 [W,B,S,H] -> kvin bf16 [B, w*S+s, H] --------
__global__ __launch_bounds__(256) void cache2kv(const float* __restrict__ cache,
                                                u16* __restrict__ kvin) {
  int blk = blockIdx.x;          // cB*cW*cS = 8192
  int b = blk >> 12, w = (blk >> 10) & 3, s = blk & 1023;
  const float* src = cache + ((size_t)((w * cB + b) * cS + s)) * cH;
  u16* dst = kvin + ((size_t)(b * cL + w * cS + s)) * cH;
  int t = threadIdx.x;
  float4 v = *(const float4*)(src + t * 4);
  ushort4 o; u16* op = (u16*)&o;
  op[0] = f2u(v.x); op[1] = f2u(v.y); op[2] = f2u(v.z); op[3] = f2u(v.w);
  *(ushort4*)(dst + t * 4) = o;
}

// -------- weight transpose: W f32 [k][n] -> Wt bf16 [n][k], 4 matrices --------
__global__ __launch_bounds__(256) void wtrans(
    const float* __restrict__ W0, const float* __restrict__ W1,
    const float* __restrict__ W2, const float* __restrict__ W3,
    u16* __restrict__ Wt)
{
  __shared__ float tile[32][33];
  int mat = blockIdx.z;
  const float* W = (mat == 0) ? W0 : (mat == 1) ? W1 : (mat == 2) ? W2 : W3;
  u16* out = Wt + (size_t)mat * cH * cH;
  int k0 = blockIdx.y * 32, n0 = blockIdx.x * 32;
  int t = threadIdx.x;
  int r = t >> 3, c = (t & 7) * 4;
  float4 v = *(const float4*)(W + (size_t)(k0 + r) * cH + n0 + c);
  tile[r][c] = v.x; tile[r][c + 1] = v.y; tile[r][c + 2] = v.z; tile[r][c + 3] = v.w;
  __syncthreads();
  ushort4 o; u16* op = (u16*)&o;
  #pragma unroll
  for (int j = 0; j < 4; j++) op[j] = f2u(tile[c + j][r]);
  *(ushort4*)(out + (size_t)(n0 + r) * cH + k0 + c) = o;
}

// ---------------- MFMA GEMM: C[M,1024] = A(bf16)[M,1024] @ W, Wt=[n][k] bf16 ----------------
// mode 1: bf16 head-major out [b][h][localrow][d]   (c_rpb = rows per batch)
// mode 2: gated-residual epilogue -> f32 outp
// mode 3: bf16 V^T out [b][h][d][localrow] via LDS transpose
constexpr int GBM = 128, GBN = 128, GLD = 40, TLD = 136;

__global__ __launch_bounds__(256) void mgemm(
    const u16* __restrict__ A, const u16* __restrict__ Wt,
    int a_rpb, int a_base, int a_stride,
    int c_rpb, int mode,
    u16* __restrict__ Cb,
    const float* __restrict__ hidden, const float* __restrict__ cachefull,
    const float* __restrict__ gate, const float* __restrict__ lsc,
    float* __restrict__ outp)
{
  __shared__ __align__(16) u16 smem[128 * TLD];   // 34.8 KB (union: As+Bs | t2)
  u16* As = smem;              // [128][GLD]
  u16* Bs = smem + 128 * GLD;  // [128][GLD]

  int t = threadIdx.x;
  int m0 = blockIdx.y * GBM, n0 = blockIdx.x * GBN;
  int wave = t >> 6, lane = t & 63, l15 = lane & 15, quad = lane >> 4;
  int wm = (wave >> 1) * 64, wn = (wave & 1) * 64;

  int sr = t >> 2, sk = (t & 3) * 8;
  int rg0 = m0 + sr, rg1 = rg0 + 64;
  int ab0 = rg0 / a_rpb, ab1 = rg1 / a_rpb;
  const u16* arow0 = A + (size_t)(ab0 * a_stride + a_base + (rg0 - ab0 * a_rpb)) * cH + sk;
  const u16* arow1 = A + (size_t)(ab1 * a_stride + a_base + (rg1 - ab1 * a_rpb)) * cH + sk;
  const u16* wrow0 = Wt + (size_t)(n0 + sr) * cH + sk;
  const u16* wrow1 = Wt + (size_t)(n0 + sr + 64) * cH + sk;

  f32x4 acc[4][4] = {};

  for (int k0 = 0; k0 < cH; k0 += 32) {
    uint4 a0 = *(const uint4*)(arow0 + k0);
    uint4 a1 = *(const uint4*)(arow1 + k0);
    uint4 b0 = *(const uint4*)(wrow0 + k0);
    uint4 b1 = *(const uint4*)(wrow1 + k0);
    __syncthreads();
    *(uint4*)&As[sr * GLD + sk] = a0;
    *(uint4*)&As[(sr + 64) * GLD + sk] = a1;
    *(uint4*)&Bs[sr * GLD + sk] = b0;
    *(uint4*)&Bs[(sr + 64) * GLD + sk] = b1;
    __syncthreads();
    s16x8 af[4], bf[4];
    #pragma unroll
    for (int mt = 0; mt < 4; mt++)
      af[mt] = *(const s16x8*)&As[(wm + mt * 16 + l15) * GLD + quad * 8];
    #pragma unroll
    for (int nt = 0; nt < 4; nt++)
      bf[nt] = *(const s16x8*)&Bs[(wn + nt * 16 + l15) * GLD + quad * 8];
    #pragma unroll
    for (int mt = 0; mt < 4; mt++)
      #pragma unroll
      for (int nt = 0; nt < 4; nt++)
        acc[mt][nt] = __builtin_amdgcn_mfma_f32_16x16x32_bf16(af[mt], bf[nt], acc[mt][nt], 0, 0, 0);
  }

  if (mode == 1) {
    // bf16 head-major: [b][h][localrow][d]
    #pragma unroll
    for (int mt = 0; mt < 4; mt++)
      #pragma unroll
      for (int i = 0; i < 4; i++) {
        int rg = m0 + wm + mt * 16 + quad * 4 + i;
        int bo = rg / c_rpb, lo = rg - bo * c_rpb;
        #pragma unroll
        for (int nt = 0; nt < 4; nt++) {
          int n = n0 + wn + nt * 16 + l15;
          int h = n >> 6, d = n & 63;
          Cb[(((size_t)(bo * cNH + h) * c_rpb + lo) * cHD) + d] = f2u(acc[mt][nt][i]);
        }
      }
  } else if (mode == 3) {
    // V^T via LDS transpose: t2[n_local][m_local]
    u16* t2 = smem;
    __syncthreads();
    #pragma unroll
    for (int mt = 0; mt < 4; mt++)
      #pragma unroll
      for (int nt = 0; nt < 4; nt++) {
        ushort4 o; u16* op = (u16*)&o;
        #pragma unroll
        for (int i = 0; i < 4; i++) op[i] = f2u(acc[mt][nt][i]);
        *(ushort4*)&t2[(size_t)(wn + nt * 16 + l15) * TLD + wm + mt * 16 + quad * 4] = o;
      }
    __syncthreads();
    int n_l = t >> 1, mh = (t & 1) * 64;
    int bo = m0 / c_rpb;                 // 128 | c_rpb boundaries
    int lo = m0 - bo * c_rpb + mh;
    int n = n0 + n_l, h = n >> 6, d = n & 63;
    u16* dst = Cb + ((size_t)(bo * cNH + h) * cHD + d) * (size_t)c_rpb + lo;
    #pragma unroll
    for (int j = 0; j < 8; j++)
      *(uint4*)(dst + j * 8) = *(const uint4*)&t2[(size_t)n_l * TLD + mh + j * 8];
  } else {
    // gated-residual epilogue -> f32
    float gv[4], lv[4];
    #pragma unroll
    for (int nt = 0; nt < 4; nt++) {
      int n = n0 + wn + nt * 16 + l15;
      gv[nt] = 1.f / (1.f + __expf(-gate[n]));
      lv[nt] = lsc[n];
    }
    #pragma unroll
    for (int mt = 0; mt < 4; mt++)
      #pragma unroll
      for (int i = 0; i < 4; i++) {
        int rg = m0 + wm + mt * 16 + quad * 4 + i;
        size_t rbase = (size_t)rg * cH;
        #pragma unroll
        for (int nt = 0; nt < 4; nt++) {
          int n = n0 + wn + nt * 16 + l15;
          float hid = hidden[rbase + n];
          float cr = cachefull[(size_t)3 * cB * cS * cH + rbase + n];
          outp[rbase + n] = hid + lv[nt] * (gv[nt] * acc[mt][nt][i] + (1.f - gv[nt]) * cr);
        }
      }
  }
}

// ---------------- RoPE in-place on head-major bf16 [b*h][rows][64] ----------------
__global__ __launch_bounds__(256) void rope_b16(u16* __restrict__ X, int rows) {
  size_t idx = (size_t)blockIdx.x * 256 + threadIdx.x;
  int d = (int)(idx & 31);
  size_t rest = idx >> 5;
  int row = (int)(rest % rows);
  size_t bh = rest / rows;
  u16* xp = X + (bh * rows + row) * cHD;
  int pos = row & (cS - 1);
  float freq = exp2f(-(float)d * (13.287712379549449f / 32.f)); // 10000^(-d/32)
  float ang = (float)pos * freq;
  float sn, cs;
  sincosf(ang, &sn, &cs);
  float x1 = u2f(xp[d]), x2 = u2f(xp[d + 32]);
  xp[d] = f2u(x1 * cs - x2 * sn);
  xp[d + 32] = f2u(x1 * sn + x2 * cs);
}

// ---------------- MFMA flash attention (ctx -> bf16) ----------------
constexpr int ACK = 64;
constexpr int PLD = 72;

__global__ __launch_bounds__(256) void attn_mfma(
    const u16* __restrict__ Q, const u16* __restrict__ K, const u16* __restrict__ Vt,
    u16* __restrict__ ctx)
{
  __shared__ u16 pbuf[4][16 * PLD];

  int t = threadIdx.x;
  int wave = t >> 6, lane = t & 63;
  int l15 = lane & 15, quad = lane >> 4;
  int qt = blockIdx.x, h = blockIdx.y, b = blockIdx.z;
  int q0 = qt * 64 + wave * 16;

  const u16* qp = Q + ((size_t)(b * cNH + h) * cS + q0) * cHD;
  const u16* kp = K + (size_t)(b * cNH + h) * cL * cHD;
  const u16* vp = Vt + (size_t)(b * cNH + h) * cHD * cL;
  u16* pw = pbuf[wave];

  s16x8 qf0 = ld_frag(qp + (size_t)l15 * cHD + quad * 8);
  s16x8 qf1 = ld_frag(qp + (size_t)l15 * cHD + 32 + quad * 8);

  f32x4 oacc[4] = {};
  float mrow[4], lrow[4];
  #pragma unroll
  for (int i = 0; i < 4; i++) { mrow[i] = -1e30f; lrow[i] = 0.f; }

  constexpr float SCL = 0.125f * 1.4426950408889634f;

  for (int kt = 0; kt < cL / ACK; kt++) {
    const u16* kc = kp + (size_t)kt * ACK * cHD;
    f32x4 sc[4];
    #pragma unroll
    for (int nt = 0; nt < 4; nt++) {
      s16x8 kf0 = ld_frag(kc + (size_t)(nt * 16 + l15) * cHD + quad * 8);
      s16x8 kf1 = ld_frag(kc + (size_t)(nt * 16 + l15) * cHD + 32 + quad * 8);
      f32x4 a = {};
      a = __builtin_amdgcn_mfma_f32_16x16x32_bf16(qf0, kf0, a, 0, 0, 0);
      a = __builtin_amdgcn_mfma_f32_16x16x32_bf16(qf1, kf1, a, 0, 0, 0);
      sc[nt] = a * SCL;
    }
    float mx[4];
    #pragma unroll
    for (int i = 0; i < 4; i++)
      mx[i] = fmaxf(fmaxf(sc[0][i], sc[1][i]), fmaxf(sc[2][i], sc[3][i]));
    #pragma unroll
    for (int off = 1; off < 16; off <<= 1)
      #pragma unroll
      for (int i = 0; i < 4; i++) mx[i] = fmaxf(mx[i], __shfl_xor(mx[i], off));
    float alpha[4];
    #pragma unroll
    for (int i = 0; i < 4; i++) {
      float mn = fmaxf(mrow[i], mx[i]);
      alpha[i] = exp2f(mrow[i] - mn);
      mrow[i] = mn;
    }
    float ps[4] = {};
    #pragma unroll
    for (int nt = 0; nt < 4; nt++)
      #pragma unroll
      for (int i = 0; i < 4; i++) {
        float p = exp2f(sc[nt][i] - mrow[i]);
        ps[i] += p;
        pw[(quad * 4 + i) * PLD + nt * 16 + l15] = f2u(p);
      }
    #pragma unroll
    for (int off = 1; off < 16; off <<= 1)
      #pragma unroll
      for (int i = 0; i < 4; i++) ps[i] += __shfl_xor(ps[i], off);
    #pragma unroll
    for (int i = 0; i < 4; i++) lrow[i] = lrow[i] * alpha[i] + ps[i];
    #pragma unroll
    for (int dt = 0; dt < 4; dt++)
      #pragma unroll
      for (int i = 0; i < 4; i++) oacc[dt][i] *= alpha[i];
    s16x8 pf0 = *(const s16x8*)&pw[l15 * PLD + quad * 8];
    s16x8 pf1 = *(const s16x8*)&pw[l15 * PLD + 32 + quad * 8];
    #pragma unroll
    for (int dt = 0; dt < 4; dt++) {
      const u16* vr = vp + (size_t)(dt * 16 + l15) * cL + kt * ACK;
      s16x8 vf0 = ld_frag(vr + quad * 8);
      s16x8 vf1 = ld_frag(vr + 32 + quad * 8);
      oacc[dt] = __builtin_amdgcn_mfma_f32_16x16x32_bf16(pf0, vf0, oacc[dt], 0, 0, 0);
      oacc[dt] = __builtin_amdgcn_mfma_f32_16x16x32_bf16(pf1, vf1, oacc[dt], 0, 0, 0);
    }
  }
  #pragma unroll
  for (int i = 0; i < 4; i++) {
    float inv = 1.f / lrow[i];
    int q = q0 + quad * 4 + i;
    u16* crow = ctx + ((size_t)b * cS + q) * cH + h * cHD;
    #pragma unroll
    for (int dt = 0; dt < 4; dt++)
      crow[dt * 16 + l15] = f2u(oacc[dt][i] * inv);
  }
}

extern "C" void kernel_launch(void* const* d_in, const int* in_sizes, int n_in,
                              void* d_out, int out_size, void* d_ws, size_t ws_size,
                              hipStream_t stream)
{
  const float* hidden = (const float*)d_in[0];
  const float* cache  = (const float*)d_in[1];
  const float* ln_s   = (const float*)d_in[2];
  const float* ln_b   = (const float*)d_in[3];
  const float* Wq     = (const float*)d_in[4];
  const float* Wk     = (const float*)d_in[5];
  const float* Wv     = (const float*)d_in[6];
  const float* Wo     = (const float*)d_in[7];
  const float* gate   = (const float*)d_in[8];
  const float* lsc    = (const float*)d_in[9];
  float* outp = (float*)d_out;

  // workspace: kvin [0,20.97M), vt [20.97M,41.94M)
  u16* kvin = (u16*)d_ws;
  u16* vt   = kvin + (size_t)cB * cL * cH;
  // aliases into kvin (dead rows by the time these are written):
  u16* qb  = kvin;                               // [0,4MB): written by Q GEMM (last kvin reader)
  u16* ctx = kvin + (size_t)2 * 1024 * 1024;     // [4,8MB): written by attention
  // scratch parked in d_out (overwritten by memcpy/final-LN at the end):
  u16* kb = (u16*)(outp + (size_t)cB * cS * cH);                 // cache-slot-0..2 region
  u16* Wt = (u16*)(outp + (size_t)(1 + 3) * cB * cS * cH);       // cache-slot-3 region (8.39MB exact)
  u16* Wt_q = Wt;
  u16* Wt_k = Wt + (size_t)cH * cH;
  u16* Wt_v = Wt + (size_t)2 * cH * cH;
  u16* Wt_o = Wt + (size_t)3 * cH * cH;

  // 1) weight transpose+convert: W[k][n] f32 -> Wt[n][k] bf16
  wtrans<<<dim3(32, 32, 4), 256, 0, stream>>>(Wq, Wk, Wv, Wo, Wt);
  // 2) cache -> kvin head rows (bf16, permuted)
  cache2kv<<<cB * cW * cS, 256, 0, stream>>>(cache, kvin);
  // 3) pre-norm -> kvin tail rows (bf16)
  ln_bf16<<<cB * cS, 256, 0, stream>>>(hidden, kvin, ln_s, ln_b);

  // 4) K/V/Q projections (MFMA)
  mgemm<<<dim3(8, (cB * cL) / GBM), 256, 0, stream>>>(
      kvin, Wt_k, cL, 0, cL, cL, 1, kb, nullptr, nullptr, nullptr, nullptr, nullptr);
  mgemm<<<dim3(8, (cB * cL) / GBM), 256, 0, stream>>>(
      kvin, Wt_v, cL, 0, cL, cL, 3, vt, nullptr, nullptr, nullptr, nullptr, nullptr);
  mgemm<<<dim3(8, (cB * cS) / GBM), 256, 0, stream>>>(
      kvin, Wt_q, cS, cW * cS, cL, cS, 1, qb, nullptr, nullptr, nullptr, nullptr, nullptr);

  // 5) RoPE on Q and K
  rope_b16<<<(cB * cNH * cS * 32) / 256, 256, 0, stream>>>(qb, cS);
  rope_b16<<<(cB * cNH * cL * 32) / 256, 256, 0, stream>>>(kb, cL);

  // 6) MFMA flash attention -> ctx (bf16, token-major)
  attn_mfma<<<dim3(cS / 64, cNH, cB), 256, 0, stream>>>(qb, kb, vt, ctx);

  // 7) ctx @ Wo with fused gated residual -> output f32
  mgemm<<<dim3(8, (cB * cS) / GBM), 256, 0, stream>>>(
      ctx, Wt_o, cB * cS, 0, cB * cS, cB * cS, 2, nullptr,
      hidden, cache, gate, lsc, outp);

  // 8) new_cache[0:3] = cache[1:4] (overwrites kb scratch — kb is dead now)
  hipMemcpyAsync(outp + (size_t)cB * cS * cH, cache + (size_t)cB * cS * cH,
                 (size_t)(cW - 1) * cB * cS * cH * sizeof(float),
                 hipMemcpyDeviceToDevice, stream);
  // 9) final layernorm -> new_cache slot 3 (overwrites Wt scratch — Wt is dead now)
  ln_f32<<<cB * cS, 256, 0, stream>>>(outp, outp + (size_t)cW * cB * cS * cH, ln_s, ln_b);
}

// Round 6
// 619.202 us; speedup vs baseline: 3.9616x; 1.0097x over previous
//
#include <hip/hip_runtime.h>
#include <math.h>

typedef unsigned short u16;

constexpr int cB = 2;
constexpr int cS = 1024;
constexpr int cH = 1024;
constexpr int cNH = 16;
constexpr int cHD = 64;
constexpr int cW = 4;
constexpr int cL = (cW + 1) * cS; // 5120
constexpr float cEPS = 1e-5f;

typedef short s16x8 __attribute__((ext_vector_type(8)));   // 8 bf16 (4 VGPRs)
typedef float f32x4 __attribute__((ext_vector_type(4)));   // MFMA C/D

__device__ __forceinline__ float u2f(u16 u) {
  union { unsigned int i; float f; } x; x.i = ((unsigned int)u) << 16; return x.f;
}
__device__ __forceinline__ u16 f2u(float f) {
  union { float f; unsigned int i; } x; x.f = f;
  unsigned int i = x.i;
  i += 0x7fffu + ((i >> 16) & 1u); // RNE
  return (u16)(i >> 16);
}
__device__ __forceinline__ s16x8 ld_frag(const u16* p) {
  uint4 v = *(const uint4*)p;
  union { uint4 u; s16x8 s; } c; c.u = v; return c.s;
}
__device__ __forceinline__ s16x8 u4_frag(uint4 v) {
  union { uint4 u; s16x8 s; } c; c.u = v; return c.s;
}

// ---------------- LayerNorm f32 -> f32 (final LN) ----------------
__global__ __launch_bounds__(256) void ln_f32(
    const float* __restrict__ src, float* __restrict__ dst,
    const float* __restrict__ scale, const float* __restrict__ bias)
{
  int r = blockIdx.x;
  int t = threadIdx.x;
  const float* sp = src + (size_t)r * cH;
  float4 x = ((const float4*)sp)[t];
  float s1 = x.x + x.y + x.z + x.w;
  float s2 = x.x * x.x + x.y * x.y + x.z * x.z + x.w * x.w;
  #pragma unroll
  for (int off = 32; off > 0; off >>= 1) {
    s1 += __shfl_down(s1, off);
    s2 += __shfl_down(s2, off);
  }
  __shared__ float w1[4], w2[4];
  __shared__ float stat[2];
  int wid = t >> 6, lid = t & 63;
  if (lid == 0) { w1[wid] = s1; w2[wid] = s2; }
  __syncthreads();
  if (t == 0) {
    float a = w1[0] + w1[1] + w1[2] + w1[3];
    float b = w2[0] + w2[1] + w2[2] + w2[3];
    float mu = a * (1.f / cH);
    float var = b * (1.f / cH) - mu * mu;
    if (var < 0.f) var = 0.f;
    stat[0] = mu; stat[1] = rsqrtf(var + cEPS);
  }
  __syncthreads();
  float mu = stat[0], rs = stat[1];
  int h0 = t * 4;
  float4 sc = *(const float4*)(scale + h0);
  float4 bi = *(const float4*)(bias + h0);
  float4 o;
  o.x = (x.x - mu) * rs * sc.x + bi.x;
  o.y = (x.y - mu) * rs * sc.y + bi.y;
  o.z = (x.z - mu) * rs * sc.z + bi.z;
  o.w = (x.w - mu) * rs * sc.w + bi.w;
  *(float4*)(dst + (size_t)r * cH + h0) = o;
}

// ---------------- LayerNorm f32 -> bf16 into kvin tail ----------------
__global__ __launch_bounds__(256) void ln_bf16(
    const float* __restrict__ src, u16* __restrict__ kvin,
    const float* __restrict__ scale, const float* __restrict__ bias)
{
  int r = blockIdx.x;            // 0..cB*cS-1
  int t = threadIdx.x;
  const float* sp = src + (size_t)r * cH;
  float4 x = ((const float4*)sp)[t];
  float s1 = x.x + x.y + x.z + x.w;
  float s2 = x.x * x.x + x.y * x.y + x.z * x.z + x.w * x.w;
  #pragma unroll
  for (int off = 32; off > 0; off >>= 1) {
    s1 += __shfl_down(s1, off);
    s2 += __shfl_down(s2, off);
  }
  __shared__ float w1[4], w2[4];
  __shared__ float stat[2];
  int wid = t >> 6, lid = t & 63;
  if (lid == 0) { w1[wid] = s1; w2[wid] = s2; }
  __syncthreads();
  if (t == 0) {
    float a = w1[0] + w1[1] + w1[2] + w1[3];
    float b = w2[0] + w2[1] + w2[2] + w2[3];
    float mu = a * (1.f / cH);
    float var = b * (1.f / cH) - mu * mu;
    if (var < 0.f) var = 0.f;
    stat[0] = mu; stat[1] = rsqrtf(var + cEPS);
  }
  __syncthreads();
  float mu = stat[0], rs = stat[1];
  int h0 = t * 4;
  float4 sc = *(const float4*)(scale + h0);
  float4 bi = *(const float4*)(bias + h0);
  int b = r >> 10, s = r & (cS - 1);
  u16* dp = kvin + ((size_t)(b * cL + cW * cS + s)) * cH + h0;
  ushort4 o; u16* op = (u16*)&o;
  op[0] = f2u((x.x - mu) * rs * sc.x + bi.x);
  op[1] = f2u((x.y - mu) * rs * sc.y + bi.y);
  op[2] = f2u((x.z - mu) * rs * sc.z + bi.z);
  op[3] = f2u((x.w - mu) * rs * sc.w + bi.w);
  *(ushort4*)dp = o;
}

// -------- cache f32 [W,B,S,H] -> kvin bf16 [B, w*S+s, H] --------
__global__ __launch_bounds__(256) void cache2kv(const float* __restrict__ cache,
                                                u16* __restrict__ kvin) {
  int blk = blockIdx.x;          // cB*cW*cS = 8192
  int b = blk >> 12, w = (blk >> 10) & 3, s = blk & 1023;
  const float* src = cache + ((size_t)((w * cB + b) * cS + s)) * cH;
  u16* dst = kvin + ((size_t)(b * cL + w * cS + s)) * cH;
  int t = threadIdx.x;
  float4 v = *(const float4*)(src + t * 4);
  ushort4 o; u16* op = (u16*)&o;
  op[0] = f2u(v.x); op[1] = f2u(v.y); op[2] = f2u(v.z); op[3] = f2u(v.w);
  *(ushort4*)(dst + t * 4) = o;
}

// -------- weight transpose: W f32 [k][n] -> Wt bf16 [n][k], 4 matrices --------
__global__ __launch_bounds__(256) void wtrans(
    const float* __restrict__ W0, const float* __restrict__ W1,
    const float* __restrict__ W2, const float* __restrict__ W3,
    u16* __restrict__ Wt)
{
  __shared__ float tile[32][33];
  int mat = blockIdx.z;
  const float* W = (mat == 0) ? W0 : (mat == 1) ? W1 : (mat == 2) ? W2 : W3;
  u16* out = Wt + (size_t)mat * cH * cH;
  int k0 = blockIdx.y * 32, n0 = blockIdx.x * 32;
  int t = threadIdx.x;
  int r = t >> 3, c = (t & 7) * 4;
  float4 v = *(const float4*)(W + (size_t)(k0 + r) * cH + n0 + c);
  tile[r][c] = v.x; tile[r][c + 1] = v.y; tile[r][c + 2] = v.z; tile[r][c + 3] = v.w;
  __syncthreads();
  ushort4 o; u16* op = (u16*)&o;
  #pragma unroll
  for (int j = 0; j < 4; j++) op[j] = f2u(tile[c + j][r]);
  *(ushort4*)(out + (size_t)(n0 + r) * cH + k0 + c) = o;
}

// ---------------- MFMA GEMM: C[M,1024] = A(bf16)[M,1024] @ W, Wt=[n][k] bf16 ----------------
constexpr int GBM = 128, GBN = 128, GLD = 40, TLD = 136;

__global__ __launch_bounds__(256) void mgemm(
    const u16* __restrict__ A, const u16* __restrict__ Wt,
    int a_rpb, int a_base, int a_stride,
    int c_rpb, int mode,
    u16* __restrict__ Cb,
    const float* __restrict__ hidden, const float* __restrict__ cachefull,
    const float* __restrict__ gate, const float* __restrict__ lsc,
    float* __restrict__ outp)
{
  __shared__ __align__(16) u16 smem[128 * TLD];
  u16* As = smem;              // [128][GLD]
  u16* Bs = smem + 128 * GLD;  // [128][GLD]

  int t = threadIdx.x;
  int m0 = blockIdx.y * GBM, n0 = blockIdx.x * GBN;
  int wave = t >> 6, lane = t & 63, l15 = lane & 15, quad = lane >> 4;
  int wm = (wave >> 1) * 64, wn = (wave & 1) * 64;

  int sr = t >> 2, sk = (t & 3) * 8;
  int rg0 = m0 + sr, rg1 = rg0 + 64;
  int ab0 = rg0 / a_rpb, ab1 = rg1 / a_rpb;
  const u16* arow0 = A + (size_t)(ab0 * a_stride + a_base + (rg0 - ab0 * a_rpb)) * cH + sk;
  const u16* arow1 = A + (size_t)(ab1 * a_stride + a_base + (rg1 - ab1 * a_rpb)) * cH + sk;
  const u16* wrow0 = Wt + (size_t)(n0 + sr) * cH + sk;
  const u16* wrow1 = Wt + (size_t)(n0 + sr + 64) * cH + sk;

  f32x4 acc[4][4] = {};

  for (int k0 = 0; k0 < cH; k0 += 32) {
    uint4 a0 = *(const uint4*)(arow0 + k0);
    uint4 a1 = *(const uint4*)(arow1 + k0);
    uint4 b0 = *(const uint4*)(wrow0 + k0);
    uint4 b1 = *(const uint4*)(wrow1 + k0);
    __syncthreads();
    *(uint4*)&As[sr * GLD + sk] = a0;
    *(uint4*)&As[(sr + 64) * GLD + sk] = a1;
    *(uint4*)&Bs[sr * GLD + sk] = b0;
    *(uint4*)&Bs[(sr + 64) * GLD + sk] = b1;
    __syncthreads();
    s16x8 af[4], bf[4];
    #pragma unroll
    for (int mt = 0; mt < 4; mt++)
      af[mt] = *(const s16x8*)&As[(wm + mt * 16 + l15) * GLD + quad * 8];
    #pragma unroll
    for (int nt = 0; nt < 4; nt++)
      bf[nt] = *(const s16x8*)&Bs[(wn + nt * 16 + l15) * GLD + quad * 8];
    #pragma unroll
    for (int mt = 0; mt < 4; mt++)
      #pragma unroll
      for (int nt = 0; nt < 4; nt++)
        acc[mt][nt] = __builtin_amdgcn_mfma_f32_16x16x32_bf16(af[mt], bf[nt], acc[mt][nt], 0, 0, 0);
  }

  if (mode == 1) {
    #pragma unroll
    for (int mt = 0; mt < 4; mt++)
      #pragma unroll
      for (int i = 0; i < 4; i++) {
        int rg = m0 + wm + mt * 16 + quad * 4 + i;
        int bo = rg / c_rpb, lo = rg - bo * c_rpb;
        #pragma unroll
        for (int nt = 0; nt < 4; nt++) {
          int n = n0 + wn + nt * 16 + l15;
          int h = n >> 6, d = n & 63;
          Cb[(((size_t)(bo * cNH + h) * c_rpb + lo) * cHD) + d] = f2u(acc[mt][nt][i]);
        }
      }
  } else if (mode == 3) {
    u16* t2 = smem;
    __syncthreads();
    #pragma unroll
    for (int mt = 0; mt < 4; mt++)
      #pragma unroll
      for (int nt = 0; nt < 4; nt++) {
        ushort4 o; u16* op = (u16*)&o;
        #pragma unroll
        for (int i = 0; i < 4; i++) op[i] = f2u(acc[mt][nt][i]);
        *(ushort4*)&t2[(size_t)(wn + nt * 16 + l15) * TLD + wm + mt * 16 + quad * 4] = o;
      }
    __syncthreads();
    int n_l = t >> 1, mh = (t & 1) * 64;
    int bo = m0 / c_rpb;
    int lo = m0 - bo * c_rpb + mh;
    int n = n0 + n_l, h = n >> 6, d = n & 63;
    u16* dst = Cb + ((size_t)(bo * cNH + h) * cHD + d) * (size_t)c_rpb + lo;
    #pragma unroll
    for (int j = 0; j < 8; j++)
      *(uint4*)(dst + j * 8) = *(const uint4*)&t2[(size_t)n_l * TLD + mh + j * 8];
  } else {
    float gv[4], lv[4];
    #pragma unroll
    for (int nt = 0; nt < 4; nt++) {
      int n = n0 + wn + nt * 16 + l15;
      gv[nt] = 1.f / (1.f + __expf(-gate[n]));
      lv[nt] = lsc[n];
    }
    #pragma unroll
    for (int mt = 0; mt < 4; mt++)
      #pragma unroll
      for (int i = 0; i < 4; i++) {
        int rg = m0 + wm + mt * 16 + quad * 4 + i;
        size_t rbase = (size_t)rg * cH;
        #pragma unroll
        for (int nt = 0; nt < 4; nt++) {
          int n = n0 + wn + nt * 16 + l15;
          float hid = hidden[rbase + n];
          float cr = cachefull[(size_t)3 * cB * cS * cH + rbase + n];
          outp[rbase + n] = hid + lv[nt] * (gv[nt] * acc[mt][nt][i] + (1.f - gv[nt]) * cr);
        }
      }
  }
}

// ---------------- RoPE in-place on head-major bf16 [b*h][rows][64] ----------------
__global__ __launch_bounds__(256) void rope_b16(u16* __restrict__ X, int rows) {
  size_t idx = (size_t)blockIdx.x * 256 + threadIdx.x;
  int d = (int)(idx & 31);
  size_t rest = idx >> 5;
  int row = (int)(rest % rows);
  size_t bh = rest / rows;
  u16* xp = X + (bh * rows + row) * cHD;
  int pos = row & (cS - 1);
  float freq = exp2f(-(float)d * (13.287712379549449f / 32.f)); // 10000^(-d/32)
  float ang = (float)pos * freq;
  float sn, cs;
  sincosf(ang, &sn, &cs);
  float x1 = u2f(xp[d]), x2 = u2f(xp[d + 32]);
  xp[d] = f2u(x1 * cs - x2 * sn);
  xp[d + 32] = f2u(x1 * sn + x2 * cs);
}

// ---------------- MFMA flash attention, split-K over key halves ----------------
// blockIdx.z = b*2+split.  Outputs unnormalized partial O (f32) + (m,l) per row.
constexpr int ACK = 64;
constexpr int PLD = 72;
constexpr int KSPLIT = 2;
constexpr int KS = cL / KSPLIT;      // 2560 keys per split

__global__ __launch_bounds__(256, 4) void attn_mfma(
    const u16* __restrict__ Q, const u16* __restrict__ K, const u16* __restrict__ Vt,
    float* __restrict__ opart, float* __restrict__ mlbuf)
{
  __shared__ u16 pbuf[4][16 * PLD];

  int t = threadIdx.x;
  int wave = t >> 6, lane = t & 63;
  int l15 = lane & 15, quad = lane >> 4;
  int qt = blockIdx.x, h = blockIdx.y;
  int bz = blockIdx.z;
  int b = bz >> 1, split = bz & 1;
  int q0 = qt * 64 + wave * 16;
  int kbase = split * KS;

  const u16* qp = Q + ((size_t)(b * cNH + h) * cS + q0) * cHD;
  const u16* kp = K + ((size_t)(b * cNH + h) * cL + kbase) * cHD;
  const u16* vp = Vt + (size_t)(b * cNH + h) * cHD * cL + kbase;
  u16* pw = pbuf[wave];

  s16x8 qf0 = ld_frag(qp + (size_t)l15 * cHD + quad * 8);
  s16x8 qf1 = ld_frag(qp + (size_t)l15 * cHD + 32 + quad * 8);

  f32x4 oacc[4] = {};
  float mrow[4], lrow[4];
  #pragma unroll
  for (int i = 0; i < 4; i++) { mrow[i] = -1e30f; lrow[i] = 0.f; }

  constexpr float SCL = 0.125f * 1.4426950408889634f;

  for (int kt = 0; kt < KS / ACK; kt++) {
    // ---- hoisted V loads (latency covered by scores+softmax below) ----
    uint4 vreg[8];
    #pragma unroll
    for (int dt = 0; dt < 4; dt++) {
      const u16* vr = vp + (size_t)(dt * 16 + l15) * cL + kt * ACK;
      vreg[2 * dt]     = *(const uint4*)(vr + quad * 8);
      vreg[2 * dt + 1] = *(const uint4*)(vr + 32 + quad * 8);
    }
    const u16* kc = kp + (size_t)kt * ACK * cHD;
    f32x4 sc[4];
    #pragma unroll
    for (int nt = 0; nt < 4; nt++) {
      s16x8 kf0 = ld_frag(kc + (size_t)(nt * 16 + l15) * cHD + quad * 8);
      s16x8 kf1 = ld_frag(kc + (size_t)(nt * 16 + l15) * cHD + 32 + quad * 8);
      f32x4 a = {};
      a = __builtin_amdgcn_mfma_f32_16x16x32_bf16(qf0, kf0, a, 0, 0, 0);
      a = __builtin_amdgcn_mfma_f32_16x16x32_bf16(qf1, kf1, a, 0, 0, 0);
      sc[nt] = a * SCL;
    }
    float mx[4];
    #pragma unroll
    for (int i = 0; i < 4; i++)
      mx[i] = fmaxf(fmaxf(sc[0][i], sc[1][i]), fmaxf(sc[2][i], sc[3][i]));
    #pragma unroll
    for (int off = 1; off < 16; off <<= 1)
      #pragma unroll
      for (int i = 0; i < 4; i++) mx[i] = fmaxf(mx[i], __shfl_xor(mx[i], off));
    float alpha[4];
    #pragma unroll
    for (int i = 0; i < 4; i++) {
      float mn = fmaxf(mrow[i], mx[i]);
      alpha[i] = exp2f(mrow[i] - mn);
      mrow[i] = mn;
    }
    float ps[4] = {};
    #pragma unroll
    for (int nt = 0; nt < 4; nt++)
      #pragma unroll
      for (int i = 0; i < 4; i++) {
        float p = exp2f(sc[nt][i] - mrow[i]);
        ps[i] += p;
        pw[(quad * 4 + i) * PLD + nt * 16 + l15] = f2u(p);
      }
    #pragma unroll
    for (int off = 1; off < 16; off <<= 1)
      #pragma unroll
      for (int i = 0; i < 4; i++) ps[i] += __shfl_xor(ps[i], off);
    #pragma unroll
    for (int i = 0; i < 4; i++) lrow[i] = lrow[i] * alpha[i] + ps[i];
    #pragma unroll
    for (int dt = 0; dt < 4; dt++)
      #pragma unroll
      for (int i = 0; i < 4; i++) oacc[dt][i] *= alpha[i];
    s16x8 pf0 = *(const s16x8*)&pw[l15 * PLD + quad * 8];
    s16x8 pf1 = *(const s16x8*)&pw[l15 * PLD + 32 + quad * 8];
    #pragma unroll
    for (int dt = 0; dt < 4; dt++) {
      oacc[dt] = __builtin_amdgcn_mfma_f32_16x16x32_bf16(pf0, u4_frag(vreg[2 * dt]), oacc[dt], 0, 0, 0);
      oacc[dt] = __builtin_amdgcn_mfma_f32_16x16x32_bf16(pf1, u4_frag(vreg[2 * dt + 1]), oacc[dt], 0, 0, 0);
    }
  }
  // ---- epilogue: unnormalized partial O + (m,l) ----
  #pragma unroll
  for (int i = 0; i < 4; i++) {
    int q = q0 + quad * 4 + i;
    size_t R = ((size_t)(split * cB + b) * cNH + h) * cS + q;
    float* orow = opart + R * cHD;
    #pragma unroll
    for (int dt = 0; dt < 4; dt++)
      orow[dt * 16 + l15] = oacc[dt][i];
    if (l15 == 0) {
      mlbuf[R * 2] = mrow[i];
      mlbuf[R * 2 + 1] = lrow[i];
    }
  }
}

// ---------------- split-K merge: combine two softmax partials -> bf16 ctx ----------------
__global__ __launch_bounds__(256) void attn_merge(
    const float* __restrict__ opart, const float* __restrict__ mlbuf,
    u16* __restrict__ ctx)
{
  int t = threadIdx.x;
  int R = blockIdx.x * 4 + (t >> 6);   // (b*cNH+h)*cS + q
  int d = t & 63;
  const size_t NR = (size_t)cB * cNH * cS;
  float m1 = mlbuf[(size_t)R * 2],        l1 = mlbuf[(size_t)R * 2 + 1];
  float m2 = mlbuf[(NR + R) * 2],         l2 = mlbuf[(NR + R) * 2 + 1];
  float m = fmaxf(m1, m2);
  float a1 = exp2f(m1 - m), a2 = exp2f(m2 - m);
  float inv = 1.f / (l1 * a1 + l2 * a2);
  float o1 = opart[(size_t)R * cHD + d];
  float o2 = opart[(NR + R) * cHD + d];
  float val = (o1 * a1 + o2 * a2) * inv;
  int q = R & (cS - 1), h = (R >> 10) & 15, b = R >> 14;
  ctx[((size_t)b * cS + q) * cH + h * cHD + d] = f2u(val);
}

extern "C" void kernel_launch(void* const* d_in, const int* in_sizes, int n_in,
                              void* d_out, int out_size, void* d_ws, size_t ws_size,
                              hipStream_t stream)
{
  const float* hidden = (const float*)d_in[0];
  const float* cache  = (const float*)d_in[1];
  const float* ln_s   = (const float*)d_in[2];
  const float* ln_b   = (const float*)d_in[3];
  const float* Wq     = (const float*)d_in[4];
  const float* Wk     = (const float*)d_in[5];
  const float* Wv     = (const float*)d_in[6];
  const float* Wo     = (const float*)d_in[7];
  const float* gate   = (const float*)d_in[8];
  const float* lsc    = (const float*)d_in[9];
  float* outp = (float*)d_out;

  // ws: kvin 20.97M | vt 20.97M | opart 16.78M | ml 0.52M  (~59.3 MB)
  u16* kvin = (u16*)d_ws;
  u16* vt   = kvin + (size_t)cB * cL * cH;
  float* opart = (float*)(vt + (size_t)cB * cL * cH);
  float* mlbuf = opart + (size_t)KSPLIT * cB * cNH * cS * cHD;
  // aliases into kvin (dead rows by the time these are written):
  u16* qb  = kvin;                               // written by Q GEMM (last kvin reader)
  u16* ctx = kvin + (size_t)2 * 1024 * 1024;     // written by attn_merge
  // scratch parked in d_out (overwritten by memcpy/final-LN at the end):
  u16* kb = (u16*)(outp + (size_t)cB * cS * cH);
  u16* Wt = (u16*)(outp + (size_t)(1 + 3) * cB * cS * cH);
  u16* Wt_q = Wt;
  u16* Wt_k = Wt + (size_t)cH * cH;
  u16* Wt_v = Wt + (size_t)2 * cH * cH;
  u16* Wt_o = Wt + (size_t)3 * cH * cH;

  // 1) weight transpose+convert
  wtrans<<<dim3(32, 32, 4), 256, 0, stream>>>(Wq, Wk, Wv, Wo, Wt);
  // 2) cache -> kvin head rows (bf16, permuted)
  cache2kv<<<cB * cW * cS, 256, 0, stream>>>(cache, kvin);
  // 3) pre-norm -> kvin tail rows (bf16)
  ln_bf16<<<cB * cS, 256, 0, stream>>>(hidden, kvin, ln_s, ln_b);

  // 4) K/V/Q projections (MFMA)
  mgemm<<<dim3(8, (cB * cL) / GBM), 256, 0, stream>>>(
      kvin, Wt_k, cL, 0, cL, cL, 1, kb, nullptr, nullptr, nullptr, nullptr, nullptr);
  mgemm<<<dim3(8, (cB * cL) / GBM), 256, 0, stream>>>(
      kvin, Wt_v, cL, 0, cL, cL, 3, vt, nullptr, nullptr, nullptr, nullptr, nullptr);
  mgemm<<<dim3(8, (cB * cS) / GBM), 256, 0, stream>>>(
      kvin, Wt_q, cS, cW * cS, cL, cS, 1, qb, nullptr, nullptr, nullptr, nullptr, nullptr);

  // 5) RoPE on Q and K
  rope_b16<<<(cB * cNH * cS * 32) / 256, 256, 0, stream>>>(qb, cS);
  rope_b16<<<(cB * cNH * cL * 32) / 256, 256, 0, stream>>>(kb, cL);

  // 6) split-K MFMA flash attention -> partials, then merge -> ctx (bf16)
  attn_mfma<<<dim3(cS / 64, cNH, cB * KSPLIT), 256, 0, stream>>>(qb, kb, vt, opart, mlbuf);
  attn_merge<<<(cB * cNH * cS) / 4, 256, 0, stream>>>(opart, mlbuf, ctx);

  // 7) ctx @ Wo with fused gated residual -> output f32
  mgemm<<<dim3(8, (cB * cS) / GBM), 256, 0, stream>>>(
      ctx, Wt_o, cB * cS, 0, cB * cS, cB * cS, 2, nullptr,
      hidden, cache, gate, lsc, outp);

  // 8) new_cache[0:3] = cache[1:4]
  hipMemcpyAsync(outp + (size_t)cB * cS * cH, cache + (size_t)cB * cS * cH,
                 (size_t)(cW - 1) * cB * cS * cH * sizeof(float),
                 hipMemcpyDeviceToDevice, stream);
  // 9) final layernorm -> new_cache slot 3
  ln_f32<<<cB * cS, 256, 0, stream>>>(outp, outp + (size_t)cW * cB * cS * cH, ln_s, ln_b);
}